// Round 13
// baseline (35.573 us; speedup 1.0000x reference)
//
#include <hip/hip_runtime.h>

// Ray-sphere intersection: N rays x 64 moving spheres -> closest hit distance.
// x: (1, N, 7) f32 = [origin(3), t_ray(1), direction(3)]
// z: (1, 384) f32 = 64 spheres x [center(3), velocity(3)]
// out: mu (N) ++ sigma (N), f32
//
// R13 = R12 (LDS-coalesced x staging + v2f packed 2-ray core) with BLK=512.
// Single-variable probe: across R2-R12 idle(dur - VALU busy) ~= 14us except
// the one 512-thread variant (R11: 7.3us). Also: thread t takes rays
// (t, t+512) so LDS readback strides are 9t and 9t+4608 dwords -- both
// conflict-free (gcd(9,32)=1; 4608 % 32 == 0); R12's paired-ray layout was a
// 4-way conflict (360K SQ_LDS_BANK_CONFLICT).
//
// FROZEN ARITHMETIC (R3/R5/R8-proven, elementwise identical):
//   oc = fma(v,t, c-o); b = fma(dx,ocx,fma(dy,ocy,dz*ocz));
//   csq = fma(ocx,ocx,fma(ocy,ocy,ocz*ocz)); disc = fma(b,b, 1-csq);
//   sq = raw v_sqrt(disc) (disc<0 -> NaN -> compares false -> BIG);
//   r = t0>0 ? t0 : (t1>0 ? t1 : BIG); closest = fmin(closest, r).
// Unsigned-bit-min tails are BANNED (failed R4, R7).

typedef float v2f __attribute__((ext_vector_type(2)));

constexpr float BIGF = 1e10f;
constexpr int BLK = 512;     // threads per block
constexpr int RPB = 1024;    // rays per block (2 per thread)
constexpr int STR = 9;       // dwords per ray in LDS (7 used + 2 pad)

__global__ __launch_bounds__(BLK, 8) void ray_sphere_kernel(
    const float* __restrict__ x, const float* __restrict__ z,
    float* __restrict__ out, int N)
{
    __shared__ float lds[RPB * STR];            // 36864 B -> 4 blocks/CU

    const int t = threadIdx.x;
    const long blockRay0 = (long)blockIdx.x * RPB;

    // ---- stage this block's 7168 x-floats into LDS, coalesced ----
    const float* xs = x + blockRay0 * 7;
    #pragma unroll
    for (int k = 0; k < 14; ++k) {
        unsigned i = (unsigned)(k * BLK + t);   // < 7168, wave-linear
        float v = xs[i];                        // 256B contiguous per instr
        unsigned r = i / 7u;                    // magic-mul
        unsigned j = i - r * 7u;
        lds[r * STR + j] = v;
    }
    __syncthreads();

    // ---- my 2 rays: t and t+512 (both readbacks conflict-free) ----
    const float* r0 = lds + t * STR;
    const float* r1 = lds + (t + BLK) * STR;
    v2f ox = {r0[0], r1[0]}, oy = {r0[1], r1[1]}, oz = {r0[2], r1[2]};
    v2f tr = {r0[3], r1[3]};
    v2f dx = {r0[4], r1[4]}, dy = {r0[5], r1[5]}, dz = {r0[6], r1[6]};

    // normalize d: d / (sqrt(|d|^2) + 1e-12)   (FROZEN)
    {
        v2f n2 = __builtin_elementwise_fma(dx, dx,
                 __builtin_elementwise_fma(dy, dy, dz * dz));
        v2f inv;
        inv[0] = __builtin_amdgcn_rcpf(__builtin_amdgcn_sqrtf(n2[0]) + 1e-12f);
        inv[1] = __builtin_amdgcn_rcpf(__builtin_amdgcn_sqrtf(n2[1]) + 1e-12f);
        dx *= inv; dy *= inv; dz *= inv;
    }

    v2f closest = {BIGF, BIGF};

    #pragma unroll 16
    for (int s = 0; s < 64; ++s) {
        const float* zs = z + s * 6;            // uniform -> s_load, SGPR
        float cx = zs[0], cy = zs[1], cz = zs[2];
        float vx = zs[3], vy = zs[4], vz = zs[5];

        // oc = (c - o) + v * t                 (FROZEN)
        v2f ocx = __builtin_elementwise_fma((v2f){vx, vx}, tr, cx - ox);
        v2f ocy = __builtin_elementwise_fma((v2f){vy, vy}, tr, cy - oy);
        v2f ocz = __builtin_elementwise_fma((v2f){vz, vz}, tr, cz - oz);
        // b = d . oc                           (FROZEN)
        v2f b = __builtin_elementwise_fma(dx, ocx,
                __builtin_elementwise_fma(dy, ocy, dz * ocz));
        // csq = |oc|^2                         (FROZEN)
        v2f csq = __builtin_elementwise_fma(ocx, ocx,
                  __builtin_elementwise_fma(ocy, ocy, ocz * ocz));
        // disc = b^2 + (1 - csq)               (FROZEN)
        v2f disc = __builtin_elementwise_fma(b, b, (v2f){1.0f, 1.0f} - csq);

        // disc<0 -> NaN -> both compares below false -> BIG
        v2f sq;
        sq[0] = __builtin_amdgcn_sqrtf(disc[0]);
        sq[1] = __builtin_amdgcn_sqrtf(disc[1]);

        v2f t0 = b - sq;
        v2f t1 = b + sq;

        #pragma unroll
        for (int k = 0; k < 2; ++k) {
            float r1v = (t1[k] > 0.0f) ? t1[k] : BIGF;   // cmp + cndmask
            float rr  = (t0[k] > 0.0f) ? t0[k] : r1v;    // cmp + cndmask
            closest[k] = fminf(closest[k], rr);          // v_min
        }
    }

    long nA = blockRay0 + t;
    long nB = nA + BLK;
    out[nA] = closest[0];          // coalesced dword stores
    out[nB] = closest[1];
    out[N + nA] = 0.002f;
    out[N + nB] = 0.002f;
}

extern "C" void kernel_launch(void* const* d_in, const int* in_sizes, int n_in,
                              void* d_out, int out_size, void* d_ws, size_t ws_size,
                              hipStream_t stream) {
    const float* x = (const float*)d_in[0];
    const float* z = (const float*)d_in[1];
    float* out = (float*)d_out;
    int N = in_sizes[0] / 7;   // 1048576

    int blocks = N / RPB;      // 1024
    ray_sphere_kernel<<<blocks, BLK, 0, stream>>>(x, z, out, N);
}